// Round 4
// baseline (34163.483 us; speedup 1.0000x reference)
//
#include <hip/hip_runtime.h>
#include <math.h>

#define BB   256   // batch
#define HH   512   // hidden
#define NWG  256
#define NTHR 1024
#define TT   64    // steps
#define NOUT 33
#define CD   128   // cond dim
#define SZ   (HH*BB)
#define LOFF (4*HH*HH)   // layer stride in Wih/Whh
#define BOFF (4*HH)      // layer stride in bih/bhh

__device__ __forceinline__ float sigm(float x)  { return 1.0f/(1.0f+expf(-x)); }
__device__ __forceinline__ float lrelu(float x) { return x >= 0.0f ? x : 0.01f*x; }

// Monotonic 2-level grid barrier: 8 group counters (32 arrivals) -> 1 global (8) -> gen.
__device__ __forceinline__ void gbar(unsigned* bar, unsigned ep, int grp) {
  __syncthreads();
  if (threadIdx.x == 0) {
    __builtin_amdgcn_fence(__ATOMIC_RELEASE, "agent");
    unsigned old = __hip_atomic_fetch_add(&bar[grp*16], 1u, __ATOMIC_RELAXED, __HIP_MEMORY_SCOPE_AGENT);
    if (old == ep*32u + 31u) {
      unsigned o2 = __hip_atomic_fetch_add(&bar[128], 1u, __ATOMIC_RELAXED, __HIP_MEMORY_SCOPE_AGENT);
      if (o2 == ep*8u + 7u)
        __hip_atomic_store(&bar[144], ep+1u, __ATOMIC_RELAXED, __HIP_MEMORY_SCOPE_AGENT);
    }
    while (__hip_atomic_load(&bar[144], __ATOMIC_RELAXED, __HIP_MEMORY_SCOPE_AGENT) < ep+1u)
      __builtin_amdgcn_s_sleep(8);
    __builtin_amdgcn_fence(__ATOMIC_ACQUIRE, "agent");
  }
  __syncthreads();
}

// load 4 k-steps x 2 batch cols from a [H][B] global buffer
__device__ __forceinline__ void ld4x2(const float* __restrict__ p, float* q) {
  #pragma unroll
  for (int j = 0; j < 4; ++j) {
    q[j*2]   = p[j*BB];
    q[j*2+1] = p[j*BB + 64];
  }
}

// 4 k-steps of gate GEMM: weights [k][16] from LDS (uniform b128 broadcast)
__device__ __forceinline__ void fmablk4(const float* __restrict__ wl,
                                        const float* qx, const float* qh, float* acc) {
  #pragma unroll
  for (int j = 0; j < 4; ++j) {
    const float* wr = wl + j*16;
    float4 wi0 = *(const float4*)(wr+0);
    float4 wi1 = *(const float4*)(wr+4);
    float4 wh0 = *(const float4*)(wr+8);
    float4 wh1 = *(const float4*)(wr+12);
    #pragma unroll
    for (int jj = 0; jj < 2; ++jj) {
      float x = qx[j*2+jj], h = qh[j*2+jj];
      acc[0+jj]  += wi0.x*x + wh0.x*h;
      acc[2+jj]  += wi0.y*x + wh0.y*h;
      acc[4+jj]  += wi0.z*x + wh0.z*h;
      acc[6+jj]  += wi0.w*x + wh0.w*h;
      acc[8+jj]  += wi1.x*x + wh1.x*h;
      acc[10+jj] += wi1.y*x + wh1.y*h;
      acc[12+jj] += wi1.z*x + wh1.z*h;
      acc[14+jj] += wi1.w*x + wh1.w*h;
    }
  }
}

// One LSTM layer phase. Wave = (bgroup, kslice): lane holds 2 batch rows, 8 gate rows,
// 64 k. Partials reduced via LDS red[64][BB]; pointwise by tid<512.
__device__ __forceinline__ void lstm_phase(const float* __restrict__ wl,
    const float* __restrict__ bias, float* __restrict__ red,
    const float* __restrict__ xsrc, const float* __restrict__ hsrc,
    float* __restrict__ hdst, float* __restrict__ cbuf,
    int hu0, int tid, int ks, int b0)
{
  {
    float acc[16];
    #pragma unroll
    for (int r = 0; r < 16; ++r) acc[r] = 0.0f;
    const int kbase = ks*64;
    const float* xp = xsrc + kbase*BB + b0;
    const float* hp = hsrc + kbase*BB + b0;
    float qxA[8], qhA[8], qxB[8], qhB[8];
    ld4x2(xp,        qxA); ld4x2(hp,        qhA);
    ld4x2(xp + 4*BB, qxB); ld4x2(hp + 4*BB, qhB);
    const float* wbase = wl + kbase*16;
    #pragma unroll 1
    for (int blk = 0; blk < 16; blk += 2) {
      fmablk4(wbase + blk*64, qxA, qhA, acc);
      if (blk+2 < 16) { ld4x2(xp + (blk+2)*4*BB, qxA); ld4x2(hp + (blk+2)*4*BB, qhA); }
      fmablk4(wbase + (blk+1)*64, qxB, qhB, acc);
      if (blk+3 < 16) { ld4x2(xp + (blk+3)*4*BB, qxB); ld4x2(hp + (blk+3)*4*BB, qhB); }
    }
    #pragma unroll
    for (int r = 0; r < 8; ++r) {
      red[(ks*8 + r)*BB + b0]    = acc[2*r];
      red[(ks*8 + r)*BB + b0+64] = acc[2*r+1];
    }
  }
  __syncthreads();
  if (tid < 512) {
    const int b = tid & 255, u = tid >> 8;
    float g[4];
    #pragma unroll
    for (int gg = 0; gg < 4; ++gg) {
      float s = bias[u*4+gg];
      #pragma unroll
      for (int k2 = 0; k2 < 8; ++k2) s += red[(k2*8 + u*4+gg)*BB + b];
      g[gg] = s;
    }
    const int hu = hu0 + u;
    float ig = sigm(g[0]), fg = sigm(g[1]);
    float gv = tanhf(g[2]), og = sigm(g[3]);
    float cn = fg*cbuf[hu*BB+b] + ig*gv;
    cbuf[hu*BB+b] = cn;
    hdst[hu*BB+b] = og*tanhf(cn);
  }
}

extern "C" __global__ void __launch_bounds__(NTHR, 4)
decoder_kernel(const float* __restrict__ h0, const float* __restrict__ c0,
               const float* __restrict__ conds, const float* __restrict__ emb,
               const float* __restrict__ Wih, const float* __restrict__ Whh,
               const float* __restrict__ bih, const float* __restrict__ bhh,
               const float* __restrict__ fcW, const float* __restrict__ fcb,
               const float* __restrict__ fc2W, const float* __restrict__ fc2b,
               const float* __restrict__ fc3W, const float* __restrict__ fc3b,
               float* __restrict__ out, unsigned* bar, float* wsf)
{
  const int w   = blockIdx.x;
  const int tid = threadIdx.x;
  const int hu0 = 2*w;
  const int grp = w & 7;
  const int lane = tid & 63;
  const int wv   = tid >> 6;       // wave 0..15
  const int bg   = wv & 1;         // batch half
  const int ks   = wv >> 1;        // k-slice 0..7
  const int b0   = bg*128 + lane;  // batch rows b0, b0+64

  float* xbuf  = wsf;
  float* h1b0  = wsf + 1*SZ;
  float* h1b1  = wsf + 2*SZ;
  float* h2b0  = wsf + 3*SZ;
  float* h2b1  = wsf + 4*SZ;
  float* c1b   = wsf + 5*SZ;
  float* c2b   = wsf + 6*SZ;
  float* condb = wsf + 7*SZ;
  float* yb    = wsf + 8*SZ;
  float* condY = wsf + 9*SZ;

  __shared__ float wl1[HH*16];     // 32KB [k][Wi r0..7 | Wh r0..7], r = u*4+g
  __shared__ float wl2[HH*16];     // 32KB
  __shared__ float wfc2[HH*2];     // 4KB  [k][u]
  __shared__ float red[64*BB];     // 64KB reduction scratch
  __shared__ float bias1[8], bias2[8], biasc[2];
  __shared__ float lds_y[HH];
  __shared__ float part[NOUT][17];
  __shared__ int   lds_act;

  // ---- init ----
  if (tid < 512) {
    const int b = tid & 255, u = tid >> 8;
    const int k = hu0 + u;
    xbuf[k*BB+b] = (k < HH-1) ? emb[k] : 0.0f;   // emb[SOS=0][k], dur=0
    h1b0[k*BB+b] = h0[b*HH + k];
    c1b [k*BB+b] = c0[b*HH + k];
    h2b0[k*BB+b] = h0[(BB+b)*HH + k];
    c2b [k*BB+b] = c0[(BB+b)*HH + k];
    float a = fcb[k];
    for (int q = 0; q < CD; ++q) a += conds[b*CD+q] * fcW[k*CD+q];
    condb[k*BB+b] = lrelu(a);
  }
  for (int i = tid; i < 8*HH; i += NTHR) {
    int k = i & (HH-1), ri = i >> 9;
    int u = ri >> 2, g = ri & 3;
    int row = g*HH + hu0 + u;
    wl1[k*16 + ri]     = Wih[row*HH + k];
    wl1[k*16 + 8 + ri] = Whh[row*HH + k];
    wl2[k*16 + ri]     = Wih[LOFF + row*HH + k];
    wl2[k*16 + 8 + ri] = Whh[LOFF + row*HH + k];
  }
  for (int i = tid; i < 2*HH; i += NTHR) {
    int k = i >> 1, u = i & 1;
    wfc2[k*2 + u] = fc2W[(hu0+u)*HH + k];
  }
  if (tid < 8) {
    int u = tid >> 2, g = tid & 3;
    bias1[tid] = bih[g*HH + hu0 + u] + bhh[g*HH + hu0 + u];
    bias2[tid] = bih[BOFF + g*HH + hu0 + u] + bhh[BOFF + g*HH + hu0 + u];
  }
  if (tid < 2) biasc[tid] = fc2b[hu0 + tid];

  unsigned ep = 0;
  gbar(bar, ep++, grp);

  // condY[hu][b] = cond-branch contribution through fc2 (step-invariant)
  if (tid < 512) {
    const int b = tid & 255, u = tid >> 8;
    float s = 0.0f;
    #pragma unroll 8
    for (int k = 0; k < HH; ++k) s += wfc2[k*2+u] * condb[k*BB+b];
    condY[(hu0+u)*BB + b] = s;
  }
  __syncthreads();

  for (int t = 0; t < TT; ++t) {
    const bool par = (t & 1) != 0;
    float* h1r = par ? h1b1 : h1b0;
    float* h1w = par ? h1b0 : h1b1;
    float* h2r = par ? h2b1 : h2b0;
    float* h2w = par ? h2b0 : h2b1;

    // Phase A: layer 0
    lstm_phase(wl1, bias1, red, xbuf, h1r, h1w, c1b, hu0, tid, ks, b0);
    gbar(bar, ep++, grp);
    // Phase B: layer 1
    lstm_phase(wl2, bias2, red, h1w, h2r, h2w, c2b, hu0, tid, ks, b0);
    gbar(bar, ep++, grp);
    // Phase C: y = leaky(h2 @ fc2W^T + fc2b + condY), rows hu0..hu0+1
    {
      const int b = tid & 255, s4 = tid >> 8;   // s4: k-slice of 128
      float a0 = 0.0f, a1 = 0.0f;
      const float* hp = h2w + (s4*128)*BB + b;
      const float* wp = wfc2 + (s4*128)*2;
      #pragma unroll 1
      for (int k = 0; k < 128; k += 4) {
        #pragma unroll
        for (int j = 0; j < 4; ++j) {
          float hv = hp[(k+j)*BB];
          float2 wv = *(const float2*)(wp + (k+j)*2);
          a0 += wv.x*hv; a1 += wv.y*hv;
        }
      }
      red[(s4*2+0)*BB + b] = a0;
      red[(s4*2+1)*BB + b] = a1;
    }
    __syncthreads();
    if (tid < 512) {
      const int b = tid & 255, u = tid >> 8;
      float s = biasc[u] + condY[(hu0+u)*BB + b];
      #pragma unroll
      for (int s4 = 0; s4 < 4; ++s4) s += red[(s4*2+u)*BB + b];
      yb[(hu0+u)*BB + b] = lrelu(s);
    }
    gbar(bar, ep++, grp);
    // Phase D: WG w handles batch row w: fc3, argmax, next x
    {
      if (tid < 512) lds_y[tid] = yb[tid*BB + w];
      __syncthreads();
      int o = 0, kc = 0;
      bool active = false;
      if (tid < 512)        { o = tid & 31; kc = tid >> 5; active = true; }
      else if (tid < 528)   { o = 32;       kc = tid - 512; active = true; }
      if (active) {
        float p = 0.0f;
        const float* fw = fc3W + o*HH + kc*32;
        #pragma unroll
        for (int k2 = 0; k2 < 32; ++k2) p += fw[k2] * lds_y[kc*32 + k2];
        part[o][kc] = p;
      }
      __syncthreads();
      float predv = -1e30f;
      if (tid < NOUT) {
        float s = fc3b[tid];
        #pragma unroll
        for (int kc2 = 0; kc2 < 16; ++kc2) s += part[tid][kc2];
        predv = s;
        out[(w*TT + t)*NOUT + tid] = s;
      }
      if (tid < 64) {
        float v  = (tid < 32) ? predv : -1e30f;
        int  idx = tid;
        #pragma unroll
        for (int off = 32; off > 0; off >>= 1) {
          float ov = __shfl_xor(v, off);
          int   oi = __shfl_xor(idx, off);
          if (ov > v || (ov == v && oi < idx)) { v = ov; idx = oi; }
        }
        if (tid == 0) lds_act = idx;
      }
      __syncthreads();
      const int act = lds_act;
      if (tid < 512) xbuf[tid*BB + w] = (tid < 511) ? emb[act*(HH-1) + tid] : 1.0f;
    }
    gbar(bar, ep++, grp);
  }

  // ---- postprocess row w ----
  if (tid < TT) {
    const int s = tid;
    float* po = out + (w*TT + s)*NOUT;
    float v[NOUT];
    #pragma unroll
    for (int o = 0; o < NOUT; ++o) v[o] = po[o];
    float m = v[0];
    #pragma unroll
    for (int o = 1; o < 32; ++o) m = fmaxf(m, v[o]);
    float sum = 0.0f;
    #pragma unroll
    for (int o = 0; o < 32; ++o) sum += expf(v[o] - m);
    float lse = m + logf(sum);
    #pragma unroll
    for (int o = 0; o < 32; ++o) po[o] = v[o] - lse;
    float d = v[32];
    float dm = d;
    #pragma unroll
    for (int off = 32; off > 0; off >>= 1) dm = fmaxf(dm, __shfl_xor(dm, off));
    float e = expf(d - dm);
    float es = e;
    #pragma unroll
    for (int off = 32; off > 0; off >>= 1) es += __shfl_xor(es, off);
    po[32] = e / es;
  }
}

extern "C" void kernel_launch(void* const* d_in, const int* in_sizes, int n_in,
                              void* d_out, int out_size, void* d_ws, size_t ws_size,
                              hipStream_t stream) {
  const float* h0   = (const float*)d_in[1];
  const float* c0   = (const float*)d_in[2];
  const float* cnd  = (const float*)d_in[3];
  const float* emb  = (const float*)d_in[4];
  const float* Wih  = (const float*)d_in[5];
  const float* Whh  = (const float*)d_in[6];
  const float* bih  = (const float*)d_in[7];
  const float* bhh  = (const float*)d_in[8];
  const float* fcW  = (const float*)d_in[9];
  const float* fcb  = (const float*)d_in[10];
  const float* fc2W = (const float*)d_in[11];
  const float* fc2b = (const float*)d_in[12];
  const float* fc3W = (const float*)d_in[13];
  const float* fc3b = (const float*)d_in[14];

  unsigned* bar = (unsigned*)d_ws;
  float* wsf = (float*)((char*)d_ws + 1024);

  (void)hipMemsetAsync(d_ws, 0, 1024, stream);

  hipLaunchKernelGGL(decoder_kernel, dim3(NWG), dim3(NTHR), 0, stream,
                     h0, c0, cnd, emb, Wih, Whh, bih, bhh, fcW, fcb,
                     fc2W, fc2b, fc3W, fc3b, (float*)d_out, bar, wsf);
}

// Round 5
// 34019.656 us; speedup vs baseline: 1.0042x; 1.0042x over previous
//
#include <hip/hip_runtime.h>
#include <math.h>

#define BB   256   // batch
#define HH   512   // hidden
#define NWG  256
#define NTHR 1024
#define TT   64    // steps
#define NOUT 33
#define CD   128   // cond dim
#define SZ   (HH*BB)
#define LOFF (4*HH*HH)   // layer stride in Wih/Whh
#define BOFF (4*HH)      // layer stride in bih/bhh

__device__ __forceinline__ float sigm(float x)  { return 1.0f/(1.0f+expf(-x)); }
__device__ __forceinline__ float lrelu(float x) { return x >= 0.0f ? x : 0.01f*x; }

// Monotonic 2-level grid barrier: 8 group counters (32 arrivals) -> 1 global (8) -> gen.
__device__ __forceinline__ void gbar(unsigned* bar, unsigned ep, int grp) {
  __syncthreads();
  if (threadIdx.x == 0) {
    __builtin_amdgcn_fence(__ATOMIC_RELEASE, "agent");
    unsigned old = __hip_atomic_fetch_add(&bar[grp*16], 1u, __ATOMIC_RELAXED, __HIP_MEMORY_SCOPE_AGENT);
    if (old == ep*32u + 31u) {
      unsigned o2 = __hip_atomic_fetch_add(&bar[128], 1u, __ATOMIC_RELAXED, __HIP_MEMORY_SCOPE_AGENT);
      if (o2 == ep*8u + 7u)
        __hip_atomic_store(&bar[144], ep+1u, __ATOMIC_RELAXED, __HIP_MEMORY_SCOPE_AGENT);
    }
    while (__hip_atomic_load(&bar[144], __ATOMIC_RELAXED, __HIP_MEMORY_SCOPE_AGENT) < ep+1u)
      __builtin_amdgcn_s_sleep(8);
    __builtin_amdgcn_fence(__ATOMIC_ACQUIRE, "agent");
  }
  __syncthreads();
}

// load 4 k-steps x 2 batch cols from a [H][B] global buffer
__device__ __forceinline__ void ld4x2(const float* __restrict__ p, float* q) {
  #pragma unroll
  for (int j = 0; j < 4; ++j) {
    q[j*2]   = p[j*BB];
    q[j*2+1] = p[j*BB + 64];
  }
}

// 4 k-steps of gate GEMM: weights [k][16] from LDS (uniform b128 broadcast)
__device__ __forceinline__ void fmablk4(const float* __restrict__ wl,
                                        const float* qx, const float* qh, float* acc) {
  #pragma unroll
  for (int j = 0; j < 4; ++j) {
    const float* wr = wl + j*16;
    float4 wi0 = *(const float4*)(wr+0);
    float4 wi1 = *(const float4*)(wr+4);
    float4 wh0 = *(const float4*)(wr+8);
    float4 wh1 = *(const float4*)(wr+12);
    #pragma unroll
    for (int jj = 0; jj < 2; ++jj) {
      float x = qx[j*2+jj], h = qh[j*2+jj];
      acc[0+jj]  += wi0.x*x + wh0.x*h;
      acc[2+jj]  += wi0.y*x + wh0.y*h;
      acc[4+jj]  += wi0.z*x + wh0.z*h;
      acc[6+jj]  += wi0.w*x + wh0.w*h;
      acc[8+jj]  += wi1.x*x + wh1.x*h;
      acc[10+jj] += wi1.y*x + wh1.y*h;
      acc[12+jj] += wi1.z*x + wh1.z*h;
      acc[14+jj] += wi1.w*x + wh1.w*h;
    }
  }
}

// One LSTM layer phase. Wave = (bgroup, kslice): lane holds 2 batch rows, 8 gate rows,
// 64 k. Partials reduced via LDS red[64][BB]; pointwise by tid<512.
__device__ __forceinline__ void lstm_phase(const float* __restrict__ wl,
    const float* __restrict__ bias, float* __restrict__ red,
    const float* __restrict__ xsrc, const float* __restrict__ hsrc,
    float* __restrict__ hdst, float* __restrict__ cbuf,
    int hu0, int tid, int ks, int b0)
{
  {
    float acc[16];
    #pragma unroll
    for (int r = 0; r < 16; ++r) acc[r] = 0.0f;
    const int kbase = ks*64;
    const float* xp = xsrc + kbase*BB + b0;
    const float* hp = hsrc + kbase*BB + b0;
    float qxA[8], qhA[8], qxB[8], qhB[8];
    ld4x2(xp,        qxA); ld4x2(hp,        qhA);
    ld4x2(xp + 4*BB, qxB); ld4x2(hp + 4*BB, qhB);
    const float* wbase = wl + kbase*16;
    #pragma unroll 1
    for (int blk = 0; blk < 16; blk += 2) {
      fmablk4(wbase + blk*64, qxA, qhA, acc);
      if (blk+2 < 16) { ld4x2(xp + (blk+2)*4*BB, qxA); ld4x2(hp + (blk+2)*4*BB, qhA); }
      fmablk4(wbase + (blk+1)*64, qxB, qhB, acc);
      if (blk+3 < 16) { ld4x2(xp + (blk+3)*4*BB, qxB); ld4x2(hp + (blk+3)*4*BB, qhB); }
    }
    #pragma unroll
    for (int r = 0; r < 8; ++r) {
      red[(ks*8 + r)*BB + b0]    = acc[2*r];
      red[(ks*8 + r)*BB + b0+64] = acc[2*r+1];
    }
  }
  __syncthreads();
  if (tid < 512) {
    const int b = tid & 255, u = tid >> 8;
    float g[4];
    #pragma unroll
    for (int gg = 0; gg < 4; ++gg) {
      float s = bias[u*4+gg];
      #pragma unroll
      for (int k2 = 0; k2 < 8; ++k2) s += red[(k2*8 + u*4+gg)*BB + b];
      g[gg] = s;
    }
    const int hu = hu0 + u;
    float ig = sigm(g[0]), fg = sigm(g[1]);
    float gv = tanhf(g[2]), og = sigm(g[3]);
    float cn = fg*cbuf[hu*BB+b] + ig*gv;
    cbuf[hu*BB+b] = cn;
    hdst[hu*BB+b] = og*tanhf(cn);
  }
}

extern "C" __global__ void __launch_bounds__(NTHR)
__attribute__((amdgpu_waves_per_eu(4, 4)))
decoder_kernel(const float* __restrict__ h0, const float* __restrict__ c0,
               const float* __restrict__ conds, const float* __restrict__ emb,
               const float* __restrict__ Wih, const float* __restrict__ Whh,
               const float* __restrict__ bih, const float* __restrict__ bhh,
               const float* __restrict__ fcW, const float* __restrict__ fcb,
               const float* __restrict__ fc2W, const float* __restrict__ fc2b,
               const float* __restrict__ fc3W, const float* __restrict__ fc3b,
               float* __restrict__ out, unsigned* bar, float* wsf)
{
  const int w   = blockIdx.x;
  const int tid = threadIdx.x;
  const int hu0 = 2*w;
  const int grp = w & 7;
  const int lane = tid & 63;
  const int wv   = tid >> 6;       // wave 0..15
  const int bg   = wv & 1;         // batch half
  const int ks   = wv >> 1;        // k-slice 0..7
  const int b0   = bg*128 + lane;  // batch rows b0, b0+64

  float* xbuf  = wsf;
  float* h1b0  = wsf + 1*SZ;
  float* h1b1  = wsf + 2*SZ;
  float* h2b0  = wsf + 3*SZ;
  float* h2b1  = wsf + 4*SZ;
  float* c1b   = wsf + 5*SZ;
  float* c2b   = wsf + 6*SZ;
  float* condb = wsf + 7*SZ;
  float* yb    = wsf + 8*SZ;
  float* condY = wsf + 9*SZ;

  __shared__ float wl1[HH*16];     // 32KB [k][Wi r0..7 | Wh r0..7], r = u*4+g
  __shared__ float wl2[HH*16];     // 32KB
  __shared__ float wfc2[HH*2];     // 4KB  [k][u]
  __shared__ float red[64*BB];     // 64KB reduction scratch
  __shared__ float bias1[8], bias2[8], biasc[2];
  __shared__ float lds_y[HH];
  __shared__ float part[NOUT][17];
  __shared__ int   lds_act;

  // ---- init ----
  if (tid < 512) {
    const int b = tid & 255, u = tid >> 8;
    const int k = hu0 + u;
    xbuf[k*BB+b] = (k < HH-1) ? emb[k] : 0.0f;   // emb[SOS=0][k], dur=0
    h1b0[k*BB+b] = h0[b*HH + k];
    c1b [k*BB+b] = c0[b*HH + k];
    h2b0[k*BB+b] = h0[(BB+b)*HH + k];
    c2b [k*BB+b] = c0[(BB+b)*HH + k];
    float a = fcb[k];
    for (int q = 0; q < CD; ++q) a += conds[b*CD+q] * fcW[k*CD+q];
    condb[k*BB+b] = lrelu(a);
  }
  for (int i = tid; i < 8*HH; i += NTHR) {
    int k = i & (HH-1), ri = i >> 9;
    int u = ri >> 2, g = ri & 3;
    int row = g*HH + hu0 + u;
    wl1[k*16 + ri]     = Wih[row*HH + k];
    wl1[k*16 + 8 + ri] = Whh[row*HH + k];
    wl2[k*16 + ri]     = Wih[LOFF + row*HH + k];
    wl2[k*16 + 8 + ri] = Whh[LOFF + row*HH + k];
  }
  for (int i = tid; i < 2*HH; i += NTHR) {
    int k = i >> 1, u = i & 1;
    wfc2[k*2 + u] = fc2W[(hu0+u)*HH + k];
  }
  if (tid < 8) {
    int u = tid >> 2, g = tid & 3;
    bias1[tid] = bih[g*HH + hu0 + u] + bhh[g*HH + hu0 + u];
    bias2[tid] = bih[BOFF + g*HH + hu0 + u] + bhh[BOFF + g*HH + hu0 + u];
  }
  if (tid < 2) biasc[tid] = fc2b[hu0 + tid];

  unsigned ep = 0;
  gbar(bar, ep++, grp);

  // condY[hu][b] = cond-branch contribution through fc2 (step-invariant)
  if (tid < 512) {
    const int b = tid & 255, u = tid >> 8;
    float s = 0.0f;
    #pragma unroll 8
    for (int k = 0; k < HH; ++k) s += wfc2[k*2+u] * condb[k*BB+b];
    condY[(hu0+u)*BB + b] = s;
  }
  __syncthreads();

  for (int t = 0; t < TT; ++t) {
    const bool par = (t & 1) != 0;
    float* h1r = par ? h1b1 : h1b0;
    float* h1w = par ? h1b0 : h1b1;
    float* h2r = par ? h2b1 : h2b0;
    float* h2w = par ? h2b0 : h2b1;

    // Phase A: layer 0
    lstm_phase(wl1, bias1, red, xbuf, h1r, h1w, c1b, hu0, tid, ks, b0);
    gbar(bar, ep++, grp);
    // Phase B: layer 1
    lstm_phase(wl2, bias2, red, h1w, h2r, h2w, c2b, hu0, tid, ks, b0);
    gbar(bar, ep++, grp);
    // Phase C: y = leaky(h2 @ fc2W^T + fc2b + condY), rows hu0..hu0+1
    {
      const int b = tid & 255, s4 = tid >> 8;   // s4: k-slice of 128
      float a0 = 0.0f, a1 = 0.0f;
      const float* hp = h2w + (s4*128)*BB + b;
      const float* wp = wfc2 + (s4*128)*2;
      #pragma unroll 1
      for (int k = 0; k < 128; k += 4) {
        #pragma unroll
        for (int j = 0; j < 4; ++j) {
          float hv = hp[(k+j)*BB];
          float2 wv = *(const float2*)(wp + (k+j)*2);
          a0 += wv.x*hv; a1 += wv.y*hv;
        }
      }
      red[(s4*2+0)*BB + b] = a0;
      red[(s4*2+1)*BB + b] = a1;
    }
    __syncthreads();
    if (tid < 512) {
      const int b = tid & 255, u = tid >> 8;
      float s = biasc[u] + condY[(hu0+u)*BB + b];
      #pragma unroll
      for (int s4 = 0; s4 < 4; ++s4) s += red[(s4*2+u)*BB + b];
      yb[(hu0+u)*BB + b] = lrelu(s);
    }
    gbar(bar, ep++, grp);
    // Phase D: WG w handles batch row w: fc3, argmax, next x
    {
      if (tid < 512) lds_y[tid] = yb[tid*BB + w];
      __syncthreads();
      int o = 0, kc = 0;
      bool active = false;
      if (tid < 512)        { o = tid & 31; kc = tid >> 5; active = true; }
      else if (tid < 528)   { o = 32;       kc = tid - 512; active = true; }
      if (active) {
        float p = 0.0f;
        const float* fw = fc3W + o*HH + kc*32;
        #pragma unroll
        for (int k2 = 0; k2 < 32; ++k2) p += fw[k2] * lds_y[kc*32 + k2];
        part[o][kc] = p;
      }
      __syncthreads();
      float predv = -1e30f;
      if (tid < NOUT) {
        float s = fc3b[tid];
        #pragma unroll
        for (int kc2 = 0; kc2 < 16; ++kc2) s += part[tid][kc2];
        predv = s;
        out[(w*TT + t)*NOUT + tid] = s;
      }
      if (tid < 64) {
        float v  = (tid < 32) ? predv : -1e30f;
        int  idx = tid;
        #pragma unroll
        for (int off = 32; off > 0; off >>= 1) {
          float ov = __shfl_xor(v, off);
          int   oi = __shfl_xor(idx, off);
          if (ov > v || (ov == v && oi < idx)) { v = ov; idx = oi; }
        }
        if (tid == 0) lds_act = idx;
      }
      __syncthreads();
      const int act = lds_act;
      if (tid < 512) xbuf[tid*BB + w] = (tid < 511) ? emb[act*(HH-1) + tid] : 1.0f;
    }
    gbar(bar, ep++, grp);
  }

  // ---- postprocess row w ----
  if (tid < TT) {
    const int s = tid;
    float* po = out + (w*TT + s)*NOUT;
    float v[NOUT];
    #pragma unroll
    for (int o = 0; o < NOUT; ++o) v[o] = po[o];
    float m = v[0];
    #pragma unroll
    for (int o = 1; o < 32; ++o) m = fmaxf(m, v[o]);
    float sum = 0.0f;
    #pragma unroll
    for (int o = 0; o < 32; ++o) sum += expf(v[o] - m);
    float lse = m + logf(sum);
    #pragma unroll
    for (int o = 0; o < 32; ++o) po[o] = v[o] - lse;
    float d = v[32];
    float dm = d;
    #pragma unroll
    for (int off = 32; off > 0; off >>= 1) dm = fmaxf(dm, __shfl_xor(dm, off));
    float e = expf(d - dm);
    float es = e;
    #pragma unroll
    for (int off = 32; off > 0; off >>= 1) es += __shfl_xor(es, off);
    po[32] = e / es;
  }
}

extern "C" void kernel_launch(void* const* d_in, const int* in_sizes, int n_in,
                              void* d_out, int out_size, void* d_ws, size_t ws_size,
                              hipStream_t stream) {
  const float* h0   = (const float*)d_in[1];
  const float* c0   = (const float*)d_in[2];
  const float* cnd  = (const float*)d_in[3];
  const float* emb  = (const float*)d_in[4];
  const float* Wih  = (const float*)d_in[5];
  const float* Whh  = (const float*)d_in[6];
  const float* bih  = (const float*)d_in[7];
  const float* bhh  = (const float*)d_in[8];
  const float* fcW  = (const float*)d_in[9];
  const float* fcb  = (const float*)d_in[10];
  const float* fc2W = (const float*)d_in[11];
  const float* fc2b = (const float*)d_in[12];
  const float* fc3W = (const float*)d_in[13];
  const float* fc3b = (const float*)d_in[14];

  unsigned* bar = (unsigned*)d_ws;
  float* wsf = (float*)((char*)d_ws + 1024);

  (void)hipMemsetAsync(d_ws, 0, 1024, stream);

  hipLaunchKernelGGL(decoder_kernel, dim3(NWG), dim3(NTHR), 0, stream,
                     h0, c0, cnd, emb, Wih, Whh, bih, bhh, fcW, fcb,
                     fc2W, fc2b, fc3W, fc3b, (float*)d_out, bar, wsf);
}

// Round 6
// 6935.324 us; speedup vs baseline: 4.9260x; 4.9053x over previous
//
#include <hip/hip_runtime.h>
#include <math.h>

#define BB   256   // batch
#define HH   512   // hidden
#define NWG  256
#define NTHR 1024
#define TT   64    // steps
#define NOUT 33
#define CD   128   // cond dim
#define SZ   (HH*BB)
#define LOFF (4*HH*HH)   // layer stride in Wih/Whh
#define BOFF (4*HH)      // layer stride in bih/bhh

__device__ __forceinline__ float sigm(float x)  { return 1.0f/(1.0f+expf(-x)); }
__device__ __forceinline__ float lrelu(float x) { return x >= 0.0f ? x : 0.01f*x; }

// Monotonic 2-level grid barrier: 8 group counters (32 arrivals) -> 1 global (8) -> gen.
__device__ __forceinline__ void gbar(unsigned* bar, unsigned ep, int grp) {
  __syncthreads();
  if (threadIdx.x == 0) {
    __builtin_amdgcn_fence(__ATOMIC_RELEASE, "agent");
    unsigned old = __hip_atomic_fetch_add(&bar[grp*16], 1u, __ATOMIC_RELAXED, __HIP_MEMORY_SCOPE_AGENT);
    if (old == ep*32u + 31u) {
      unsigned o2 = __hip_atomic_fetch_add(&bar[128], 1u, __ATOMIC_RELAXED, __HIP_MEMORY_SCOPE_AGENT);
      if (o2 == ep*8u + 7u)
        __hip_atomic_store(&bar[144], ep+1u, __ATOMIC_RELAXED, __HIP_MEMORY_SCOPE_AGENT);
    }
    while (__hip_atomic_load(&bar[144], __ATOMIC_RELAXED, __HIP_MEMORY_SCOPE_AGENT) < ep+1u)
      __builtin_amdgcn_s_sleep(8);
    __builtin_amdgcn_fence(__ATOMIC_ACQUIRE, "agent");
  }
  __syncthreads();
}

// One pass: 64 k-steps, 8 gate rows, ONE batch col. ~48 live VGPRs -> no spills.
// wbase: LDS weights at this k-slice, layout [k][Wi r0..7 | Wh r0..7].
__device__ __forceinline__ void lstm_pass(const float* __restrict__ wbase,
    const float* __restrict__ xp, const float* __restrict__ hp,
    float* __restrict__ redp)   // red + (ks*8)*BB + b ; row stride BB
{
  float acc[8];
  #pragma unroll
  for (int r = 0; r < 8; ++r) acc[r] = 0.0f;
  float qx[4], qh[4], px[4], ph[4];
  #pragma unroll
  for (int j = 0; j < 4; ++j) { qx[j] = xp[j*BB]; qh[j] = hp[j*BB]; }
  #pragma unroll 1
  for (int blk = 0; blk < 16; ++blk) {
    if (blk+1 < 16) {
      #pragma unroll
      for (int j = 0; j < 4; ++j) {
        px[j] = xp[(blk*4+4+j)*BB];
        ph[j] = hp[(blk*4+4+j)*BB];
      }
    }
    #pragma unroll
    for (int j = 0; j < 4; ++j) {
      const float* wr = wbase + (blk*4+j)*16;
      float4 wi0 = *(const float4*)(wr+0);
      float4 wi1 = *(const float4*)(wr+4);
      float4 wh0 = *(const float4*)(wr+8);
      float4 wh1 = *(const float4*)(wr+12);
      float x = qx[j], h = qh[j];
      acc[0] += wi0.x*x + wh0.x*h;
      acc[1] += wi0.y*x + wh0.y*h;
      acc[2] += wi0.z*x + wh0.z*h;
      acc[3] += wi0.w*x + wh0.w*h;
      acc[4] += wi1.x*x + wh1.x*h;
      acc[5] += wi1.y*x + wh1.y*h;
      acc[6] += wi1.z*x + wh1.z*h;
      acc[7] += wi1.w*x + wh1.w*h;
    }
    #pragma unroll
    for (int j = 0; j < 4; ++j) { qx[j] = px[j]; qh[j] = ph[j]; }
  }
  #pragma unroll
  for (int r = 0; r < 8; ++r) redp[r*BB] = acc[r];
}

// One LSTM layer phase. Wave = (bg, ks); two passes, each: lane owns 1 batch row,
// 8 gate rows, 64 k. Partials -> LDS red[64][BB]; pointwise by tid<512.
__device__ __forceinline__ void lstm_phase(const float* __restrict__ wl,
    const float* __restrict__ bias, float* __restrict__ red,
    const float* __restrict__ xsrc, const float* __restrict__ hsrc,
    float* __restrict__ hdst, float* __restrict__ cbuf,
    int hu0, int tid, int ks, int bg)
{
  const int lane  = tid & 63;
  const int kbase = ks*64;
  const float* wbase = wl + kbase*16;
  #pragma unroll 1
  for (int p = 0; p < 2; ++p) {
    const int b = bg*128 + p*64 + lane;
    lstm_pass(wbase, xsrc + kbase*BB + b, hsrc + kbase*BB + b, red + (ks*8)*BB + b);
  }
  __syncthreads();
  if (tid < 512) {
    const int b = tid & 255, u = tid >> 8;
    float g[4];
    #pragma unroll
    for (int gg = 0; gg < 4; ++gg) {
      float s = bias[u*4+gg];
      #pragma unroll
      for (int k2 = 0; k2 < 8; ++k2) s += red[(k2*8 + u*4+gg)*BB + b];
      g[gg] = s;
    }
    const int hu = hu0 + u;
    float ig = sigm(g[0]), fg = sigm(g[1]);
    float gv = tanhf(g[2]), og = sigm(g[3]);
    float cn = fg*cbuf[hu*BB+b] + ig*gv;
    cbuf[hu*BB+b] = cn;
    hdst[hu*BB+b] = og*tanhf(cn);
  }
}

extern "C" __global__ void __launch_bounds__(NTHR)
decoder_kernel(const float* __restrict__ h0, const float* __restrict__ c0,
               const float* __restrict__ conds, const float* __restrict__ emb,
               const float* __restrict__ Wih, const float* __restrict__ Whh,
               const float* __restrict__ bih, const float* __restrict__ bhh,
               const float* __restrict__ fcW, const float* __restrict__ fcb,
               const float* __restrict__ fc2W, const float* __restrict__ fc2b,
               const float* __restrict__ fc3W, const float* __restrict__ fc3b,
               float* __restrict__ out, unsigned* bar, float* wsf)
{
  const int w   = blockIdx.x;
  const int tid = threadIdx.x;
  const int hu0 = 2*w;
  const int grp = w & 7;
  const int wv  = tid >> 6;        // wave 0..15
  const int bg  = wv & 1;          // batch half
  const int ks  = wv >> 1;         // k-slice 0..7

  float* xbuf  = wsf;
  float* h1b0  = wsf + 1*SZ;
  float* h1b1  = wsf + 2*SZ;
  float* h2b0  = wsf + 3*SZ;
  float* h2b1  = wsf + 4*SZ;
  float* c1b   = wsf + 5*SZ;
  float* c2b   = wsf + 6*SZ;
  float* condb = wsf + 7*SZ;
  float* yb    = wsf + 8*SZ;
  float* condY = wsf + 9*SZ;

  __shared__ float wl1[HH*16];     // 32KB [k][Wi r0..7 | Wh r0..7], r = u*4+g
  __shared__ float wl2[HH*16];     // 32KB
  __shared__ float wfc2[HH*2];     // 4KB  [k][u]
  __shared__ float red[64*BB];     // 64KB reduction scratch
  __shared__ float bias1[8], bias2[8], biasc[2];
  __shared__ float lds_y[HH];
  __shared__ float part[NOUT][17];
  __shared__ int   lds_act;

  // ---- init ----
  if (tid < 512) {
    const int b = tid & 255, u = tid >> 8;
    const int k = hu0 + u;
    xbuf[k*BB+b] = (k < HH-1) ? emb[k] : 0.0f;   // emb[SOS=0][k], dur=0
    h1b0[k*BB+b] = h0[b*HH + k];
    c1b [k*BB+b] = c0[b*HH + k];
    h2b0[k*BB+b] = h0[(BB+b)*HH + k];
    c2b [k*BB+b] = c0[(BB+b)*HH + k];
    float a = fcb[k];
    const float4* cp = (const float4*)(conds + b*CD);
    const float4* wp = (const float4*)(fcW + k*CD);
    #pragma unroll 8
    for (int q = 0; q < CD/4; ++q) {
      float4 c4 = cp[q], w4 = wp[q];
      a += c4.x*w4.x + c4.y*w4.y + c4.z*w4.z + c4.w*w4.w;
    }
    condb[k*BB+b] = lrelu(a);
  }
  for (int i = tid; i < 8*HH; i += NTHR) {
    int k = i & (HH-1), ri = i >> 9;
    int u = ri >> 2, g = ri & 3;
    int row = g*HH + hu0 + u;
    wl1[k*16 + ri]     = Wih[row*HH + k];
    wl1[k*16 + 8 + ri] = Whh[row*HH + k];
    wl2[k*16 + ri]     = Wih[LOFF + row*HH + k];
    wl2[k*16 + 8 + ri] = Whh[LOFF + row*HH + k];
  }
  for (int i = tid; i < 2*HH; i += NTHR) {
    int k = i >> 1, u = i & 1;
    wfc2[k*2 + u] = fc2W[(hu0+u)*HH + k];
  }
  if (tid < 8) {
    int u = tid >> 2, g = tid & 3;
    bias1[tid] = bih[g*HH + hu0 + u] + bhh[g*HH + hu0 + u];
    bias2[tid] = bih[BOFF + g*HH + hu0 + u] + bhh[BOFF + g*HH + hu0 + u];
  }
  if (tid < 2) biasc[tid] = fc2b[hu0 + tid];

  unsigned ep = 0;
  gbar(bar, ep++, grp);

  // condY[hu][b] = cond-branch contribution through fc2 (step-invariant)
  if (tid < 512) {
    const int b = tid & 255, u = tid >> 8;
    float s = 0.0f;
    #pragma unroll 8
    for (int k = 0; k < HH; ++k) s += wfc2[k*2+u] * condb[k*BB+b];
    condY[(hu0+u)*BB + b] = s;
  }
  __syncthreads();

  for (int t = 0; t < TT; ++t) {
    const bool par = (t & 1) != 0;
    float* h1r = par ? h1b1 : h1b0;
    float* h1w = par ? h1b0 : h1b1;
    float* h2r = par ? h2b1 : h2b0;
    float* h2w = par ? h2b0 : h2b1;

    // Phase A: layer 0
    lstm_phase(wl1, bias1, red, xbuf, h1r, h1w, c1b, hu0, tid, ks, bg);
    gbar(bar, ep++, grp);
    // Phase B: layer 1
    lstm_phase(wl2, bias2, red, h1w, h2r, h2w, c2b, hu0, tid, ks, bg);
    gbar(bar, ep++, grp);
    // Phase C: y = leaky(h2 @ fc2W^T + fc2b + condY), rows hu0..hu0+1
    {
      const int b = tid & 255, s4 = tid >> 8;   // s4: k-slice of 128
      float a0 = 0.0f, a1 = 0.0f;
      const float* hp = h2w + (s4*128)*BB + b;
      const float* wp = wfc2 + (s4*128)*2;
      #pragma unroll 1
      for (int k = 0; k < 128; k += 4) {
        #pragma unroll
        for (int j = 0; j < 4; ++j) {
          float hv = hp[(k+j)*BB];
          float2 wv = *(const float2*)(wp + (k+j)*2);
          a0 += wv.x*hv; a1 += wv.y*hv;
        }
      }
      red[(s4*2+0)*BB + b] = a0;
      red[(s4*2+1)*BB + b] = a1;
    }
    __syncthreads();
    if (tid < 512) {
      const int b = tid & 255, u = tid >> 8;
      float s = biasc[u] + condY[(hu0+u)*BB + b];
      #pragma unroll
      for (int s4 = 0; s4 < 4; ++s4) s += red[(s4*2+u)*BB + b];
      yb[(hu0+u)*BB + b] = lrelu(s);
    }
    gbar(bar, ep++, grp);
    // Phase D: WG w handles batch row w: fc3, argmax, next x
    {
      if (tid < 512) lds_y[tid] = yb[tid*BB + w];
      __syncthreads();
      int o = 0, kc = 0;
      bool active = false;
      if (tid < 512)        { o = tid & 31; kc = tid >> 5; active = true; }
      else if (tid < 528)   { o = 32;       kc = tid - 512; active = true; }
      if (active) {
        float p = 0.0f;
        const float* fw = fc3W + o*HH + kc*32;
        #pragma unroll
        for (int k2 = 0; k2 < 32; ++k2) p += fw[k2] * lds_y[kc*32 + k2];
        part[o][kc] = p;
      }
      __syncthreads();
      float predv = -1e30f;
      if (tid < NOUT) {
        float s = fc3b[tid];
        #pragma unroll
        for (int kc2 = 0; kc2 < 16; ++kc2) s += part[tid][kc2];
        predv = s;
        out[(w*TT + t)*NOUT + tid] = s;
      }
      if (tid < 64) {
        float v  = (tid < 32) ? predv : -1e30f;
        int  idx = tid;
        #pragma unroll
        for (int off = 32; off > 0; off >>= 1) {
          float ov = __shfl_xor(v, off);
          int   oi = __shfl_xor(idx, off);
          if (ov > v || (ov == v && oi < idx)) { v = ov; idx = oi; }
        }
        if (tid == 0) lds_act = idx;
      }
      __syncthreads();
      const int act = lds_act;
      if (tid < 512) xbuf[tid*BB + w] = (tid < 511) ? emb[act*(HH-1) + tid] : 1.0f;
    }
    gbar(bar, ep++, grp);
  }

  // ---- postprocess row w ----
  if (tid < TT) {
    const int s = tid;
    float* po = out + (w*TT + s)*NOUT;
    float v[NOUT];
    #pragma unroll
    for (int o = 0; o < NOUT; ++o) v[o] = po[o];
    float m = v[0];
    #pragma unroll
    for (int o = 1; o < 32; ++o) m = fmaxf(m, v[o]);
    float sum = 0.0f;
    #pragma unroll
    for (int o = 0; o < 32; ++o) sum += expf(v[o] - m);
    float lse = m + logf(sum);
    #pragma unroll
    for (int o = 0; o < 32; ++o) po[o] = v[o] - lse;
    float d = v[32];
    float dm = d;
    #pragma unroll
    for (int off = 32; off > 0; off >>= 1) dm = fmaxf(dm, __shfl_xor(dm, off));
    float e = expf(d - dm);
    float es = e;
    #pragma unroll
    for (int off = 32; off > 0; off >>= 1) es += __shfl_xor(es, off);
    po[32] = e / es;
  }
}

extern "C" void kernel_launch(void* const* d_in, const int* in_sizes, int n_in,
                              void* d_out, int out_size, void* d_ws, size_t ws_size,
                              hipStream_t stream) {
  const float* h0   = (const float*)d_in[1];
  const float* c0   = (const float*)d_in[2];
  const float* cnd  = (const float*)d_in[3];
  const float* emb  = (const float*)d_in[4];
  const float* Wih  = (const float*)d_in[5];
  const float* Whh  = (const float*)d_in[6];
  const float* bih  = (const float*)d_in[7];
  const float* bhh  = (const float*)d_in[8];
  const float* fcW  = (const float*)d_in[9];
  const float* fcb  = (const float*)d_in[10];
  const float* fc2W = (const float*)d_in[11];
  const float* fc2b = (const float*)d_in[12];
  const float* fc3W = (const float*)d_in[13];
  const float* fc3b = (const float*)d_in[14];

  unsigned* bar = (unsigned*)d_ws;
  float* wsf = (float*)((char*)d_ws + 1024);

  (void)hipMemsetAsync(d_ws, 0, 1024, stream);

  hipLaunchKernelGGL(decoder_kernel, dim3(NWG), dim3(NTHR), 0, stream,
                     h0, c0, cnd, emb, Wih, Whh, bih, bhh, fcW, fcb,
                     fc2W, fc2b, fc3W, fc3b, (float*)d_out, bar, wsf);
}